// Round 1
// baseline (477.685 us; speedup 1.0000x reference)
//
#include <hip/hip_runtime.h>
#include <math.h>

#define NS 4096
#define NF 512
#define NB 16
#define NC 10
#define HSIZE 8192
#define HMASK 8191
#define HEMPTY 0xFFFFFFFFu

// ---------------- kernel 1: per-(b,c) class counts -> ws ----------------
__global__ void count_classes_kernel(const int* __restrict__ y, float* __restrict__ counts) {
    __shared__ int hist[NC];
    const int b = blockIdx.x;
    if (threadIdx.x < NC) hist[threadIdx.x] = 0;
    __syncthreads();
    for (int s = threadIdx.x; s < NS; s += blockDim.x)
        atomicAdd(&hist[y[b * NS + s]], 1);
    __syncthreads();
    if (threadIdx.x < NC) counts[b * NC + threadIdx.x] = (float)hist[threadIdx.x];
}

// ---------------- helpers ----------------
__device__ __forceinline__ float wave_reduce_add(float v) {
    #pragma unroll
    for (int off = 32; off > 0; off >>= 1) v += __shfl_down(v, off, 64);
    return v;
}
__device__ __forceinline__ float wave_reduce_max(float v) {
    #pragma unroll
    for (int off = 32; off > 0; off >>= 1) v = fmaxf(v, __shfl_down(v, off, 64));
    return v;
}

// ---------------- kernel 2: fused stats + hash-unique + MLP ----------------
// one 256-thread workgroup per (b, f) column
// __launch_bounds__(256,4): 4 waves/EU -> 4 blocks/CU -> VGPR capped at 128
// (LDS already caps at 4 blocks/CU; don't let the batch arrays drop it to 2)
__launch_bounds__(256, 4)
__global__ void fused_stats_mlp_kernel(const float* __restrict__ X,
                                       const int* __restrict__ y,
                                       const float* __restrict__ counts,
                                       const float* __restrict__ w1,
                                       const float* __restrict__ b1,
                                       const float* __restrict__ w2,
                                       const float* __restrict__ b2,
                                       float* __restrict__ out) {
    __shared__ unsigned int hash[HSIZE];   // 32 KB open-addressing set
    __shared__ float red[4][16];
    __shared__ float stats_s[6];
    __shared__ float h_s[64];

    // XCD-aware swizzle: consecutive columns (sharing cache lines) land on one XCD
    const int w = blockIdx.x;
    const int g = (w & 7) * 1024 + (w >> 3);   // bijection over [0, 8192)
    const int b = g >> 9;
    const int f = g & (NF - 1);
    const int tid = threadIdx.x;

    #pragma unroll
    for (int i = 0; i < HSIZE / 256; i++) hash[tid + i * 256] = HEMPTY;
    __syncthreads();

    const float* Xp = X + (size_t)b * NS * NF + f;
    const int*   yp = y + b * NS;

    float sum = 0.f, sumsq = 0.f, sumabs = 0.f, maxabs = 0.f, nancnt = 0.f, uniq = 0.f;
    float csum[NC];
    #pragma unroll
    for (int c = 0; c < NC; c++) csum[c] = 0.f;

    // ---- load all 16 elements up front (independent VMEM, overlapped) ----
    float xv[16]; int yv[16];
    #pragma unroll
    for (int k = 0; k < 16; k++) {
        const int s = k * 256 + tid;
        xv[k] = Xp[(size_t)s * NF];
        yv[k] = yp[s];
    }

    // ---- streaming stats + hash preparation ----
    unsigned int pat[16], slot[16];
    #pragma unroll
    for (int k = 0; k < 16; k++) {
        float x = xv[k];
        if (x != x) { nancnt += 1.f; x = 0.f; }   // nan_to_num
        sum += x;
        sumsq = fmaf(x, x, sumsq);
        const float a = fabsf(x);
        sumabs += a;
        maxabs = fmaxf(maxabs, a);
        const int yc = yv[k];
        #pragma unroll
        for (int c = 0; c < NC; c++) csum[c] += (yc == c) ? x : 0.f;
        unsigned int p = __float_as_uint(x);
        if (p == 0x80000000u) p = 0u;             // -0.0 == +0.0 value semantics
        pat[k] = p;
        slot[k] = (p * 2654435761u) >> 19;        // top 13 bits -> [0,8192)
    }

    // ---- pipelined distinct-value insert ----
    // Round 0: issue ALL 16 independent atomicCAS back-to-back (no exec-mask
    // overhead, no dependent waits between them), THEN resolve. This replaces
    // 16 serial ~130-cycle LDS round-trips with ~1 overlapped round-trip.
    unsigned int old[16];
    #pragma unroll
    for (int k = 0; k < 16; k++)
        old[k] = atomicCAS(&hash[slot[k]], HEMPTY, pat[k]);

    int need = 0;
    #pragma unroll
    for (int k = 0; k < 16; k++) {
        if (old[k] == HEMPTY)      uniq += 1.f;        // first insertion of value
        else if (old[k] != pat[k]) need |= (1 << k);   // collision -> probe on
        // old == pat: duplicate, done
    }
    // Retry rounds: re-issue all still-pending CAS together, then resolve.
    while (need) {
        #pragma unroll
        for (int k = 0; k < 16; k++) {
            if (need & (1 << k)) {
                slot[k] = (slot[k] + 1) & HMASK;       // linear probe
                old[k] = atomicCAS(&hash[slot[k]], HEMPTY, pat[k]);
            }
        }
        #pragma unroll
        for (int k = 0; k < 16; k++) {
            if (need & (1 << k)) {
                if (old[k] == HEMPTY)      { uniq += 1.f; need &= ~(1 << k); }
                else if (old[k] == pat[k]) { need &= ~(1 << k); }
            }
        }
    }

    sum    = wave_reduce_add(sum);
    sumsq  = wave_reduce_add(sumsq);
    sumabs = wave_reduce_add(sumabs);
    nancnt = wave_reduce_add(nancnt);
    uniq   = wave_reduce_add(uniq);
    maxabs = wave_reduce_max(maxabs);
    #pragma unroll
    for (int c = 0; c < NC; c++) csum[c] = wave_reduce_add(csum[c]);

    const int wave = tid >> 6, lane = tid & 63;
    if (lane == 0) {
        red[wave][0] = sum;    red[wave][1] = sumsq; red[wave][2] = sumabs;
        red[wave][3] = nancnt; red[wave][4] = uniq;  red[wave][5] = maxabs;
        #pragma unroll
        for (int c = 0; c < NC; c++) red[wave][6 + c] = csum[c];
    }
    __syncthreads();

    if (tid == 0) {
        float t[16];
        #pragma unroll
        for (int v = 0; v < 16; v++) t[v] = red[0][v];
        #pragma unroll
        for (int wv = 1; wv < 4; wv++) {
            #pragma unroll
            for (int v = 0; v < 16; v++) {
                if (v == 5) t[v] = fmaxf(t[v], red[wv][v]);
                else        t[v] += red[wv][v];
            }
        }
        const float invS = 1.f / (float)NS;
        const float gmean    = t[0] * invS;
        const float variance = fmaxf(t[1] * invS - gmean * gmean, 0.f);  // biased var
        const float mean_abs = t[2] * invS;
        const float missing  = t[3] * invS;
        const float n_unique = t[4];
        const float max_abs  = t[5];
        float between = 0.f;
        #pragma unroll
        for (int c = 0; c < NC; c++) {
            const float cnt = counts[b * NC + c];
            const float cm  = t[6 + c] / fmaxf(cnt, 1.f);
            const float d   = cm - gmean;
            between += cnt * d * d;
        }
        between *= invS;                                   // counts.sum() == NS
        const float target = between / fmaxf(variance, 1e-6f);
        float st[6] = { target, missing, n_unique * invS, variance, mean_abs, max_abs };
        #pragma unroll
        for (int i = 0; i < 6; i++) {
            float v = st[i];
            if (!(fabsf(v) < INFINITY)) v = 0.f;           // nan_to_num(nan/±inf -> 0)
            stats_s[i] = v;
        }
    }
    __syncthreads();

    // MLP epilogue: 6 -> 64 (exact GELU) -> 128
    if (tid < 64) {
        float z = b1[tid];
        #pragma unroll
        for (int i = 0; i < 6; i++) z = fmaf(stats_s[i], w1[i * 64 + tid], z);
        h_s[tid] = 0.5f * z * (1.f + erff(z * 0.70710678118654752440f));
    }
    __syncthreads();
    if (tid < 128) {
        float o = b2[tid];
        #pragma unroll
        for (int j = 0; j < 64; j++) o = fmaf(h_s[j], w2[j * 128 + tid], o);
        out[(size_t)g * 128 + tid] = o;
    }
}

extern "C" void kernel_launch(void* const* d_in, const int* in_sizes, int n_in,
                              void* d_out, int out_size, void* d_ws, size_t ws_size,
                              hipStream_t stream) {
    const float* X  = (const float*)d_in[0];
    const int*   y  = (const int*)d_in[1];
    const float* w1 = (const float*)d_in[2];
    const float* b1 = (const float*)d_in[3];
    const float* w2 = (const float*)d_in[4];
    const float* b2 = (const float*)d_in[5];
    float* out    = (float*)d_out;
    float* counts = (float*)d_ws;          // 16*10 floats

    count_classes_kernel<<<NB, 256, 0, stream>>>(y, counts);
    fused_stats_mlp_kernel<<<NB * NF, 256, 0, stream>>>(X, y, counts, w1, b1, w2, b2, out);
}

// Round 3
// 460.454 us; speedup vs baseline: 1.0374x; 1.0374x over previous
//
#include <hip/hip_runtime.h>
#include <math.h>

#define NS 4096
#define NF 512
#define NB 16
#define NC 10
#define HSIZE 8192
#define HMASK 8191
#define HEMPTY 0xFFFFFFFFu

// ---------------- kernel 1: per-(b,c) class counts -> ws ----------------
__global__ void count_classes_kernel(const int* __restrict__ y, float* __restrict__ counts) {
    __shared__ int hist[NC];
    const int b = blockIdx.x;
    if (threadIdx.x < NC) hist[threadIdx.x] = 0;
    __syncthreads();
    for (int s = threadIdx.x; s < NS; s += blockDim.x)
        atomicAdd(&hist[y[b * NS + s]], 1);
    __syncthreads();
    if (threadIdx.x < NC) counts[b * NC + threadIdx.x] = (float)hist[threadIdx.x];
}

// ---------------- helpers ----------------
__device__ __forceinline__ float wave_reduce_add(float v) {
    #pragma unroll
    for (int off = 32; off > 0; off >>= 1) v += __shfl_down(v, off, 64);
    return v;
}
__device__ __forceinline__ float wave_reduce_max(float v) {
    #pragma unroll
    for (int off = 32; off > 0; off >>= 1) v = fmaxf(v, __shfl_down(v, off, 64));
    return v;
}

// ---------------- kernel 2: fused stats + hash-unique + MLP ----------------
// one 256-thread workgroup per (b, f) column.
// LDS = EXACTLY 32 KB (hash region aliased for csum table / reductions / MLP)
// -> 5 blocks/CU (160 KB exact), 20 waves/CU. launch_bounds(256,5) caps VGPR.
__launch_bounds__(256, 5)
__global__ void fused_stats_mlp_kernel(const float* __restrict__ X,
                                       const int* __restrict__ y,
                                       const float* __restrict__ counts,
                                       const float* __restrict__ w1,
                                       const float* __restrict__ b1,
                                       const float* __restrict__ w2,
                                       const float* __restrict__ b2,
                                       float* __restrict__ out) {
    __shared__ __align__(16) unsigned int hash[HSIZE];   // 32 KB, multi-purpose

    // XCD-aware swizzle: consecutive columns (sharing cache lines) land on one XCD
    const int w = blockIdx.x;
    const int g = (w & 7) * 1024 + (w >> 3);   // bijection over [0, 8192)
    const int b = g >> 9;
    const int f = g & (NF - 1);
    const int tid = threadIdx.x;
    const int wave = tid >> 6, lane = tid & 63;

    // ---- phase A: streaming stats; per-class sums via no-return LDS atomics ----
    // csum table [4 waves][10 classes] aliased at the base of the hash region.
    float* csumtab = (float*)hash;
    if (tid < 4 * NC) csumtab[tid] = 0.f;
    __syncthreads();

    const float* Xp = X + (size_t)b * NS * NF + f;
    const int*   yp = y + b * NS;

    float sum = 0.f, sumsq = 0.f, sumabs = 0.f, maxabs = 0.f, nancnt = 0.f;
    unsigned int pat[16];                       // survives into phase B (16 VGPR)

    #pragma unroll
    for (int k0 = 0; k0 < 16; k0 += 8) {
        float xv[8]; int yv[8];
        #pragma unroll
        for (int k = 0; k < 8; k++) {           // independent loads, overlapped
            const int s = (k0 + k) * 256 + tid;
            xv[k] = Xp[(size_t)s * NF];
            yv[k] = yp[s];
        }
        #pragma unroll
        for (int k = 0; k < 8; k++) {
            float x = xv[k];
            if (x != x) { nancnt += 1.f; x = 0.f; }   // nan_to_num
            sum += x;
            sumsq = fmaf(x, x, sumsq);
            const float a = fabsf(x);
            sumabs += a;
            maxabs = fmaxf(maxabs, a);
            // ds_add_f32 (no return value -> no dependent latency chain),
            // replaces the 10-way compare/select chain (~30 VALU/elem)
            atomicAdd(&csumtab[wave * NC + yv[k]], x);
            unsigned int p = __float_as_uint(x);
            if (p == 0x80000000u) p = 0u;             // -0.0 == +0.0 value semantics
            pat[k0 + k] = p;
        }
    }
    __syncthreads();

    // gather per-class totals into registers of lanes 0..9 of wave 0
    // (registers survive the hash phase overwriting this LDS region)
    float my_csum = 0.f;
    if (tid < NC)
        my_csum = csumtab[tid] + csumtab[NC + tid] +
                  csumtab[2 * NC + tid] + csumtab[3 * NC + tid];
    __syncthreads();

    // ---- phase B: distinct-value count via open-addressing hash ----
    // vectorized init: 8x ds_write_b128 per thread
    uint4* h4 = (uint4*)hash;
    const uint4 e4 = make_uint4(HEMPTY, HEMPTY, HEMPTY, HEMPTY);
    #pragma unroll
    for (int i = 0; i < HSIZE / 4 / 256; i++) h4[i * 256 + tid] = e4;
    __syncthreads();

    float uniq = 0.f;
    #pragma unroll
    for (int k = 0; k < 16; k++) {
        const unsigned int p = pat[k];
        unsigned int slot = (p * 2654435761u) >> 19;   // top 13 bits -> [0,8192)
        unsigned int step = 0;
        for (;;) {
            const unsigned int old = atomicCAS(&hash[slot], HEMPTY, p);
            if (old == HEMPTY) { uniq += 1.f; break; } // first insertion
            if (old == p) break;                        // duplicate
            slot = (slot + (++step)) & HMASK;           // triangular probe:
        }                                               // full-cycle on pow2 tables,
    }                                                   // table can never fill (<=4096/8192)
    __syncthreads();   // all CAS complete before re-aliasing the hash region

    // ---- phase C: block reduction + final stats (aliased into hash region) ----
    float (*red)[8] = (float(*)[8])hash;       // floats [0,32)
    float* stats_s  = (float*)hash + 64;       // floats [64,70)
    float* h_s      = (float*)hash + 128;      // floats [128,192)

    sum    = wave_reduce_add(sum);
    sumsq  = wave_reduce_add(sumsq);
    sumabs = wave_reduce_add(sumabs);
    nancnt = wave_reduce_add(nancnt);
    uniq   = wave_reduce_add(uniq);
    maxabs = wave_reduce_max(maxabs);

    if (lane == 0) {
        red[wave][0] = sum;    red[wave][1] = sumsq; red[wave][2] = sumabs;
        red[wave][3] = nancnt; red[wave][4] = uniq;  red[wave][5] = maxabs;
    }
    __syncthreads();

    if (tid < 64) {                            // wave 0: all lanes compute (uniform)
        float t0 = 0.f, t1 = 0.f, t2 = 0.f, t3 = 0.f, t4 = 0.f, t5 = 0.f;
        #pragma unroll
        for (int wv = 0; wv < 4; wv++) {       // same-address reads -> broadcast
            t0 += red[wv][0]; t1 += red[wv][1]; t2 += red[wv][2];
            t3 += red[wv][3]; t4 += red[wv][4];
            t5 = fmaxf(t5, red[wv][5]);
        }
        const float invS = 1.f / (float)NS;
        const float gmean    = t0 * invS;
        const float variance = fmaxf(t1 * invS - gmean * gmean, 0.f);  // biased var
        const float mean_abs = t2 * invS;
        const float missing  = t3 * invS;
        const float n_unique = t4;
        const float max_abs  = t5;
        float between = 0.f;
        #pragma unroll
        for (int c = 0; c < NC; c++) {
            const float csv = __shfl(my_csum, c, 64);   // per-class sum from lane c
            const float cnt = counts[b * NC + c];
            const float cm  = csv / fmaxf(cnt, 1.f);
            const float d   = cm - gmean;
            between = fmaf(cnt * d, d, between);
        }
        between *= invS;                                   // counts.sum() == NS
        const float target = between / fmaxf(variance, 1e-6f);
        if (lane == 0) {
            float st[6] = { target, missing, n_unique * invS, variance, mean_abs, max_abs };
            #pragma unroll
            for (int i = 0; i < 6; i++) {
                float v = st[i];
                if (!(fabsf(v) < INFINITY)) v = 0.f;       // nan_to_num(nan/±inf -> 0)
                stats_s[i] = v;
            }
        }
    }
    __syncthreads();

    // ---- MLP epilogue: 6 -> 64 (exact GELU) -> 128 ----
    if (tid < 64) {
        float z = b1[tid];
        #pragma unroll
        for (int i = 0; i < 6; i++) z = fmaf(stats_s[i], w1[i * 64 + tid], z);
        h_s[tid] = 0.5f * z * (1.f + erff(z * 0.70710678118654752440f));
    }
    __syncthreads();
    if (tid < 128) {
        float o = b2[tid];
        #pragma unroll
        for (int j = 0; j < 64; j++) o = fmaf(h_s[j], w2[j * 128 + tid], o);
        out[(size_t)g * 128 + tid] = o;
    }
}

extern "C" void kernel_launch(void* const* d_in, const int* in_sizes, int n_in,
                              void* d_out, int out_size, void* d_ws, size_t ws_size,
                              hipStream_t stream) {
    const float* X  = (const float*)d_in[0];
    const int*   y  = (const int*)d_in[1];
    const float* w1 = (const float*)d_in[2];
    const float* b1 = (const float*)d_in[3];
    const float* w2 = (const float*)d_in[4];
    const float* b2 = (const float*)d_in[5];
    float* out    = (float*)d_out;
    float* counts = (float*)d_ws;          // 16*10 floats

    count_classes_kernel<<<NB, 256, 0, stream>>>(y, counts);
    fused_stats_mlp_kernel<<<NB * NF, 256, 0, stream>>>(X, y, counts, w1, b1, w2, b2, out);
}

// Round 4
// 378.086 us; speedup vs baseline: 1.2634x; 1.2179x over previous
//
#include <hip/hip_runtime.h>
#include <math.h>

#define NS 4096
#define NF 512
#define NB 16
#define NC 10
#define HSIZE 8192
#define HMASK 8191
#define HEMPTY 0xFFFFFFFFu
#define WS_XT_OFF 1024   // bytes reserved for counts at base of workspace

// ---------------- kernel 1: per-(b,c) class counts -> ws ----------------
__global__ void count_classes_kernel(const int* __restrict__ y, float* __restrict__ counts) {
    __shared__ int hist[NC];
    const int b = blockIdx.x;
    if (threadIdx.x < NC) hist[threadIdx.x] = 0;
    __syncthreads();
    for (int s = threadIdx.x; s < NS; s += blockDim.x)
        atomicAdd(&hist[y[b * NS + s]], 1);
    __syncthreads();
    if (threadIdx.x < NC) counts[b * NC + threadIdx.x] = (float)hist[threadIdx.x];
}

// ---------------- helpers ----------------
__device__ __forceinline__ float wave_reduce_add(float v) {
    #pragma unroll
    for (int off = 32; off > 0; off >>= 1) v += __shfl_down(v, off, 64);
    return v;
}
__device__ __forceinline__ float wave_reduce_max(float v) {
    #pragma unroll
    for (int off = 32; off > 0; off >>= 1) v = fmaxf(v, __shfl_down(v, off, 64));
    return v;
}

// ---------------- kernel T: tiled transpose X[b,s,f] -> XT[b,f,s] ----------------
// 64x64 tile per block, float4 on both sides, LDS [64][65] kills bank conflicts.
__launch_bounds__(256)
__global__ void transpose_kernel(const float* __restrict__ X, float* __restrict__ XT) {
    __shared__ float t[64][65];
    const int b  = blockIdx.x;
    const int s0 = blockIdx.y * 64;
    const int f0 = blockIdx.z * 64;
    const int tid = threadIdx.x;

    const int fi = (tid & 15) * 4;     // 0..60
    const int si = tid >> 4;           // 0..15
    const float* Xb = X + ((size_t)b * NS + s0) * NF + f0;
    #pragma unroll
    for (int i = 0; i < 4; i++) {
        const int s = si + 16 * i;
        const float4 v = *(const float4*)(Xb + (size_t)s * NF + fi);
        t[s][fi + 0] = v.x; t[s][fi + 1] = v.y;
        t[s][fi + 2] = v.z; t[s][fi + 3] = v.w;
    }
    __syncthreads();

    const int sj = (tid & 15) * 4;
    const int fj = tid >> 4;
    float* XTb = XT + ((size_t)b * NF + f0) * NS + s0;
    #pragma unroll
    for (int i = 0; i < 4; i++) {
        const int f = fj + 16 * i;
        float4 v;
        v.x = t[sj + 0][f]; v.y = t[sj + 1][f];
        v.z = t[sj + 2][f]; v.w = t[sj + 3][f];
        *(float4*)(XTb + (size_t)f * NS + sj) = v;
    }
}

// ---------------- kernel 2 (fast): fused stats + hash-unique + MLP on XT ----------
// one 256-thread workgroup per (b, f) column; column is CONTIGUOUS in XT ->
// float4/int4 fully-coalesced loads (256 line-touches/block vs 4096 strided).
__launch_bounds__(256)
__global__ void fused_stats_mlp_xt(const float* __restrict__ XT,
                                   const int* __restrict__ y,
                                   const float* __restrict__ counts,
                                   const float* __restrict__ w1,
                                   const float* __restrict__ b1,
                                   const float* __restrict__ w2,
                                   const float* __restrict__ b2,
                                   float* __restrict__ out) {
    __shared__ unsigned int hash[HSIZE];   // 32 KB open-addressing set
    __shared__ float red[4][16];
    __shared__ float stats_s[6];
    __shared__ float h_s[64];

    const int w = blockIdx.x;
    const int g = (w & 7) * 1024 + (w >> 3);   // XCD swizzle, bijection over [0,8192)
    const int b = g >> 9;
    const int f = g & (NF - 1);
    const int tid = threadIdx.x;

    #pragma unroll
    for (int i = 0; i < HSIZE / 256; i++) hash[tid + i * 256] = HEMPTY;
    __syncthreads();

    const float4* Xc4 = (const float4*)(XT + ((size_t)b * NF + f) * NS);
    const int4*   yp4 = (const int4*)(y + (size_t)b * NS);

    float sum = 0.f, sumsq = 0.f, sumabs = 0.f, maxabs = 0.f, nancnt = 0.f, uniq = 0.f;
    float csum[NC];
    #pragma unroll
    for (int c = 0; c < NC; c++) csum[c] = 0.f;

    // all loads issued up front: 4x float4 + 4x int4 = 32 VGPR, fully overlapped
    float4 xv[4]; int4 yv[4];
    #pragma unroll
    for (int k = 0; k < 4; k++) {
        xv[k] = Xc4[k * 256 + tid];
        yv[k] = yp4[k * 256 + tid];
    }

    #pragma unroll
    for (int k = 0; k < 4; k++) {
        const float xe[4] = { xv[k].x, xv[k].y, xv[k].z, xv[k].w };
        const int   ye[4] = { yv[k].x, yv[k].y, yv[k].z, yv[k].w };
        #pragma unroll
        for (int j = 0; j < 4; j++) {
            float x = xe[j];
            if (x != x) { nancnt += 1.f; x = 0.f; }   // nan_to_num
            sum += x;
            sumsq = fmaf(x, x, sumsq);
            const float a = fabsf(x);
            sumabs += a;
            maxabs = fmaxf(maxabs, a);
            const int yc = ye[j];
            #pragma unroll
            for (int c = 0; c < NC; c++) csum[c] += (yc == c) ? x : 0.f;
            // distinct-value insert (value-equality: -0.0 == +0.0, NaN -> 0)
            unsigned int pat = __float_as_uint(x);
            if (pat == 0x80000000u) pat = 0u;
            unsigned int slot = (pat * 2654435761u) >> 19;   // top 13 bits
            for (;;) {
                const unsigned int old = atomicCAS(&hash[slot], HEMPTY, pat);
                if (old == HEMPTY) { uniq += 1.f; break; }
                if (old == pat) break;
                slot = (slot + 1) & HMASK;                    // linear probe
            }
        }
    }

    sum    = wave_reduce_add(sum);
    sumsq  = wave_reduce_add(sumsq);
    sumabs = wave_reduce_add(sumabs);
    nancnt = wave_reduce_add(nancnt);
    uniq   = wave_reduce_add(uniq);
    maxabs = wave_reduce_max(maxabs);
    #pragma unroll
    for (int c = 0; c < NC; c++) csum[c] = wave_reduce_add(csum[c]);

    const int wave = tid >> 6, lane = tid & 63;
    if (lane == 0) {
        red[wave][0] = sum;    red[wave][1] = sumsq; red[wave][2] = sumabs;
        red[wave][3] = nancnt; red[wave][4] = uniq;  red[wave][5] = maxabs;
        #pragma unroll
        for (int c = 0; c < NC; c++) red[wave][6 + c] = csum[c];
    }
    __syncthreads();

    if (tid == 0) {
        float t[16];
        #pragma unroll
        for (int v = 0; v < 16; v++) t[v] = red[0][v];
        #pragma unroll
        for (int wv = 1; wv < 4; wv++) {
            #pragma unroll
            for (int v = 0; v < 16; v++) {
                if (v == 5) t[v] = fmaxf(t[v], red[wv][v]);
                else        t[v] += red[wv][v];
            }
        }
        const float invS = 1.f / (float)NS;
        const float gmean    = t[0] * invS;
        const float variance = fmaxf(t[1] * invS - gmean * gmean, 0.f);
        const float mean_abs = t[2] * invS;
        const float missing  = t[3] * invS;
        const float n_unique = t[4];
        const float max_abs  = t[5];
        float between = 0.f;
        #pragma unroll
        for (int c = 0; c < NC; c++) {
            const float cnt = counts[b * NC + c];
            const float cm  = t[6 + c] / fmaxf(cnt, 1.f);
            const float d   = cm - gmean;
            between += cnt * d * d;
        }
        between *= invS;
        const float target = between / fmaxf(variance, 1e-6f);
        float st[6] = { target, missing, n_unique * invS, variance, mean_abs, max_abs };
        #pragma unroll
        for (int i = 0; i < 6; i++) {
            float v = st[i];
            if (!(fabsf(v) < INFINITY)) v = 0.f;
            stats_s[i] = v;
        }
    }
    __syncthreads();

    if (tid < 64) {
        float z = b1[tid];
        #pragma unroll
        for (int i = 0; i < 6; i++) z = fmaf(stats_s[i], w1[i * 64 + tid], z);
        h_s[tid] = 0.5f * z * (1.f + erff(z * 0.70710678118654752440f));
    }
    __syncthreads();
    if (tid < 128) {
        float o = b2[tid];
        #pragma unroll
        for (int j = 0; j < 64; j++) o = fmaf(h_s[j], w2[j * 128 + tid], o);
        out[(size_t)g * 128 + tid] = o;
    }
}

// ---------------- kernel 2 (fallback): round-0 strided version ----------------
__launch_bounds__(256)
__global__ void fused_stats_mlp_kernel(const float* __restrict__ X,
                                       const int* __restrict__ y,
                                       const float* __restrict__ counts,
                                       const float* __restrict__ w1,
                                       const float* __restrict__ b1,
                                       const float* __restrict__ w2,
                                       const float* __restrict__ b2,
                                       float* __restrict__ out) {
    __shared__ unsigned int hash[HSIZE];
    __shared__ float red[4][16];
    __shared__ float stats_s[6];
    __shared__ float h_s[64];

    const int w = blockIdx.x;
    const int g = (w & 7) * 1024 + (w >> 3);
    const int b = g >> 9;
    const int f = g & (NF - 1);
    const int tid = threadIdx.x;

    #pragma unroll
    for (int i = 0; i < HSIZE / 256; i++) hash[tid + i * 256] = HEMPTY;
    __syncthreads();

    const float* Xp = X + (size_t)b * NS * NF + f;
    const int*   yp = y + b * NS;

    float sum = 0.f, sumsq = 0.f, sumabs = 0.f, maxabs = 0.f, nancnt = 0.f, uniq = 0.f;
    float csum[NC];
    #pragma unroll
    for (int c = 0; c < NC; c++) csum[c] = 0.f;

    #pragma unroll
    for (int k0 = 0; k0 < 16; k0 += 8) {
        float xv[8]; int yv[8];
        #pragma unroll
        for (int k = 0; k < 8; k++) {
            const int s = (k0 + k) * 256 + tid;
            xv[k] = Xp[(size_t)s * NF];
            yv[k] = yp[s];
        }
        #pragma unroll
        for (int k = 0; k < 8; k++) {
            float x = xv[k];
            if (x != x) { nancnt += 1.f; x = 0.f; }
            sum += x;
            sumsq = fmaf(x, x, sumsq);
            const float a = fabsf(x);
            sumabs += a;
            maxabs = fmaxf(maxabs, a);
            const int yc = yv[k];
            #pragma unroll
            for (int c = 0; c < NC; c++) csum[c] += (yc == c) ? x : 0.f;
            unsigned int pat = __float_as_uint(x);
            if (pat == 0x80000000u) pat = 0u;
            unsigned int slot = (pat * 2654435761u) >> 19;
            for (;;) {
                const unsigned int old = atomicCAS(&hash[slot], HEMPTY, pat);
                if (old == HEMPTY) { uniq += 1.f; break; }
                if (old == pat) break;
                slot = (slot + 1) & HMASK;
            }
        }
    }

    sum    = wave_reduce_add(sum);
    sumsq  = wave_reduce_add(sumsq);
    sumabs = wave_reduce_add(sumabs);
    nancnt = wave_reduce_add(nancnt);
    uniq   = wave_reduce_add(uniq);
    maxabs = wave_reduce_max(maxabs);
    #pragma unroll
    for (int c = 0; c < NC; c++) csum[c] = wave_reduce_add(csum[c]);

    const int wave = tid >> 6, lane = tid & 63;
    if (lane == 0) {
        red[wave][0] = sum;    red[wave][1] = sumsq; red[wave][2] = sumabs;
        red[wave][3] = nancnt; red[wave][4] = uniq;  red[wave][5] = maxabs;
        #pragma unroll
        for (int c = 0; c < NC; c++) red[wave][6 + c] = csum[c];
    }
    __syncthreads();

    if (tid == 0) {
        float t[16];
        #pragma unroll
        for (int v = 0; v < 16; v++) t[v] = red[0][v];
        #pragma unroll
        for (int wv = 1; wv < 4; wv++) {
            #pragma unroll
            for (int v = 0; v < 16; v++) {
                if (v == 5) t[v] = fmaxf(t[v], red[wv][v]);
                else        t[v] += red[wv][v];
            }
        }
        const float invS = 1.f / (float)NS;
        const float gmean    = t[0] * invS;
        const float variance = fmaxf(t[1] * invS - gmean * gmean, 0.f);
        const float mean_abs = t[2] * invS;
        const float missing  = t[3] * invS;
        const float n_unique = t[4];
        const float max_abs  = t[5];
        float between = 0.f;
        #pragma unroll
        for (int c = 0; c < NC; c++) {
            const float cnt = counts[b * NC + c];
            const float cm  = t[6 + c] / fmaxf(cnt, 1.f);
            const float d   = cm - gmean;
            between += cnt * d * d;
        }
        between *= invS;
        const float target = between / fmaxf(variance, 1e-6f);
        float st[6] = { target, missing, n_unique * invS, variance, mean_abs, max_abs };
        #pragma unroll
        for (int i = 0; i < 6; i++) {
            float v = st[i];
            if (!(fabsf(v) < INFINITY)) v = 0.f;
            stats_s[i] = v;
        }
    }
    __syncthreads();

    if (tid < 64) {
        float z = b1[tid];
        #pragma unroll
        for (int i = 0; i < 6; i++) z = fmaf(stats_s[i], w1[i * 64 + tid], z);
        h_s[tid] = 0.5f * z * (1.f + erff(z * 0.70710678118654752440f));
    }
    __syncthreads();
    if (tid < 128) {
        float o = b2[tid];
        #pragma unroll
        for (int j = 0; j < 64; j++) o = fmaf(h_s[j], w2[j * 128 + tid], o);
        out[(size_t)g * 128 + tid] = o;
    }
}

extern "C" void kernel_launch(void* const* d_in, const int* in_sizes, int n_in,
                              void* d_out, int out_size, void* d_ws, size_t ws_size,
                              hipStream_t stream) {
    const float* X  = (const float*)d_in[0];
    const int*   y  = (const int*)d_in[1];
    const float* w1 = (const float*)d_in[2];
    const float* b1 = (const float*)d_in[3];
    const float* w2 = (const float*)d_in[4];
    const float* b2 = (const float*)d_in[5];
    float* out    = (float*)d_out;
    float* counts = (float*)d_ws;          // 16*10 floats at workspace base

    count_classes_kernel<<<NB, 256, 0, stream>>>(y, counts);

    const size_t xt_bytes = (size_t)NB * NF * NS * sizeof(float);   // 128 MB
    if (ws_size >= xt_bytes + WS_XT_OFF) {
        float* XT = (float*)((char*)d_ws + WS_XT_OFF);
        transpose_kernel<<<dim3(NB, NS / 64, NF / 64), 256, 0, stream>>>(X, XT);
        fused_stats_mlp_xt<<<NB * NF, 256, 0, stream>>>(XT, y, counts, w1, b1, w2, b2, out);
    } else {
        // workspace too small: proven strided path (round-0 structure)
        fused_stats_mlp_kernel<<<NB * NF, 256, 0, stream>>>(X, y, counts, w1, b1, w2, b2, out);
    }
}